// Round 3
// baseline (396.446 us; speedup 1.0000x reference)
//
#include <hip/hip_runtime.h>
#include <hip/hip_bf16.h>

typedef __attribute__((ext_vector_type(8))) short s8v;
typedef __attribute__((ext_vector_type(4))) float f4v;
typedef __hip_bfloat16 bf16;

#define S_LEN 2048
#define HID_DIM 2048
#define N_HEADS 16
#define HEAD_D 128
#define M_ROWS 4096
#define N_FUSED 2304  // 2048 q + 128 k + 128 v

#define EXP2F(x) __builtin_amdgcn_exp2f(x)

typedef const __attribute__((address_space(1))) unsigned gu_t;
typedef __attribute__((address_space(3))) unsigned lu_t;

static __device__ inline void gload_lds16(const bf16* g, bf16* l) {
  __builtin_amdgcn_global_load_lds((gu_t*)(const void*)g, (lu_t*)(void*)l, 16, 0, 0);
}

static __device__ inline short f2b_bits(float f) {
  bf16 h = __float2bfloat16(f);
  short u;
  __builtin_memcpy(&u, &h, 2);
  return u;
}
static __device__ inline unsigned pk_bf16(float a, float b) {
  __hip_bfloat162 h2 = __float22bfloat162_rn(float2{a, b});
  unsigned u;
  __builtin_memcpy(&u, &h2, 4);
  return u;
}

// Fragment-interior bank swizzle (bf16-index units, interior < 512):
// XOR 16B-slot bits (3-4) with row bits (6-7). Involution; applied at BOTH
// write and read sites -> placement consistent. Kills the 8-way conflict of
// [l15-row=64B][quad*16B] fragment reads (slot was 4*(l15&1)+quad; now
// 4*(l15&1) + (quad ^ ((l15>>1)&3)) -> 2 lanes/slot = free).
static __device__ inline int fswz(int i) { return i ^ (((i >> 6) & 3) << 3); }

// ---------------- fp32 -> bf16 bulk convert (5 segments, one launch) --------
struct Cvt5 {
  const float* src[5];
  bf16* dst[5];
  long n8[5];
};

__global__ __launch_bounds__(256) void cvt_f32_bf16(Cvt5 c) {
  long i = (long)blockIdx.x * 256 + threadIdx.x;
#pragma unroll
  for (int s = 0; s < 5; ++s) {
    long n8 = c.n8[s];
    if (i < n8) {
      const float* p = c.src[s] + i * 8;
      float4 f0 = *(const float4*)p;
      float4 f1 = *(const float4*)(p + 4);
      s8v t;
      t[0] = f2b_bits(f0.x); t[1] = f2b_bits(f0.y);
      t[2] = f2b_bits(f0.z); t[3] = f2b_bits(f0.w);
      t[4] = f2b_bits(f1.x); t[5] = f2b_bits(f1.y);
      t[6] = f2b_bits(f1.z); t[7] = f2b_bits(f1.w);
      *(s8v*)(c.dst[s] + i * 8) = t;
      return;
    }
    i -= n8;
  }
}

// ---------------- fused QKV GEMM (V written transposed) ---------------------
// 2-phase double-buffered staging: issue next K-tile's global_load_lds BEFORE
// computing the current tile; single __syncthreads per tile (drains vmcnt).
// Rationale: at our shapes only ~2 blocks/CU exist, so m97-style relies-on-
// co-resident-blocks overlap is absent (m102: 320 TF @N=2048) -> self-overlap.
__global__ __launch_bounds__(256, 2) void gemm_qkv(
    const bf16* __restrict__ A, const bf16* __restrict__ Wf,
    const float* __restrict__ bq, const float* __restrict__ bk,
    const float* __restrict__ bv,
    bf16* __restrict__ qout, bf16* __restrict__ kout, bf16* __restrict__ vtout) {
  __shared__ __align__(16) bf16 As[2][128 * 64];
  __shared__ __align__(16) bf16 Bs[2][128 * 64];
  const int t = threadIdx.x;
  const int lane = t & 63, wid = t >> 6;
  const int l15 = lane & 15, quad = lane >> 4;
  const int wm = wid >> 1, wn = wid & 1;
  const int bm = blockIdx.x, bn = blockIdx.y;
  const int lr = lane >> 3;        // row within 8-row chunk
  const int lc = (lane & 7) * 8;   // col elements (16B per lane)
  const bf16* Ab = &A[(size_t)(bm * 128 + lr) * HID_DIM + lc];
  const bf16* Bb = &Wf[(size_t)(bn * 128 + lr) * HID_DIM + lc];
  f4v acc[4][4] = {};
  // prologue: stage kt=0 into buffer 0
#pragma unroll
  for (int i = 0; i < 4; ++i) {
    int r0 = wid * 32 + i * 8;
    gload_lds16(Ab + (size_t)r0 * HID_DIM, &As[0][r0 * 64]);
    gload_lds16(Bb + (size_t)r0 * HID_DIM, &Bs[0][r0 * 64]);
  }
  __syncthreads();
  for (int kt = 0; kt < HID_DIM / 64; ++kt) {
    const int cur = kt & 1;
    if (kt + 1 < HID_DIM / 64) {
#pragma unroll
      for (int i = 0; i < 4; ++i) {
        int r0 = wid * 32 + i * 8;
        gload_lds16(Ab + (size_t)r0 * HID_DIM + (kt + 1) * 64, &As[cur ^ 1][r0 * 64]);
        gload_lds16(Bb + (size_t)r0 * HID_DIM + (kt + 1) * 64, &Bs[cur ^ 1][r0 * 64]);
      }
    }
#pragma unroll
    for (int ks = 0; ks < 2; ++ks) {
      s8v af[4], bfr[4];
#pragma unroll
      for (int mi = 0; mi < 4; ++mi)
        af[mi] = *(const s8v*)&As[cur][(wm * 64 + mi * 16 + l15) * 64 + ks * 32 + quad * 8];
#pragma unroll
      for (int ni = 0; ni < 4; ++ni)
        bfr[ni] = *(const s8v*)&Bs[cur][(wn * 64 + ni * 16 + l15) * 64 + ks * 32 + quad * 8];
#pragma unroll
      for (int mi = 0; mi < 4; ++mi)
#pragma unroll
        for (int ni = 0; ni < 4; ++ni)
          acc[mi][ni] = __builtin_amdgcn_mfma_f32_16x16x32_bf16(af[mi], bfr[ni], acc[mi][ni], 0, 0, 0);
    }
    __syncthreads();  // drains vmcnt (next-tile loads) + lgkmcnt (my ds_reads)
  }
  if (bn < 16) {
#pragma unroll
    for (int ni = 0; ni < 4; ++ni) {
      int cl = wn * 64 + ni * 16 + l15;
      float bvv = bq[bn * 128 + cl];
#pragma unroll
      for (int mi = 0; mi < 4; ++mi)
#pragma unroll
        for (int r = 0; r < 4; ++r) {
          int row = bm * 128 + wm * 64 + mi * 16 + quad * 4 + r;
          qout[(size_t)row * HID_DIM + bn * 128 + cl] = __float2bfloat16(acc[mi][ni][r] + bvv);
        }
    }
  } else if (bn == 16) {
#pragma unroll
    for (int ni = 0; ni < 4; ++ni) {
      int cl = wn * 64 + ni * 16 + l15;
      float bvv = bk[cl];
#pragma unroll
      for (int mi = 0; mi < 4; ++mi)
#pragma unroll
        for (int r = 0; r < 4; ++r) {
          int row = bm * 128 + wm * 64 + mi * 16 + quad * 4 + r;
          kout[(size_t)row * HEAD_D + cl] = __float2bfloat16(acc[mi][ni][r] + bvv);
        }
    }
  } else {
#pragma unroll
    for (int ni = 0; ni < 4; ++ni) {
      int cl = wn * 64 + ni * 16 + l15;
      float bvv = bv[cl];
#pragma unroll
      for (int mi = 0; mi < 4; ++mi)
#pragma unroll
        for (int r = 0; r < 4; ++r) {
          int row = bm * 128 + wm * 64 + mi * 16 + quad * 4 + r;
          vtout[(size_t)cl * M_ROWS + row] = __float2bfloat16(acc[mi][ni][r] + bvv);
        }
    }
  }
}

// ---------------- O projection -------------------------------------------
template <bool WBF>
__global__ __launch_bounds__(256, 2) void gemm_o(
    const bf16* __restrict__ A, const void* __restrict__ Wp,
    const float* __restrict__ bias, float* __restrict__ C) {
  __shared__ __align__(16) bf16 As[2][128 * 64];
  __shared__ __align__(16) bf16 Bs[2][128 * 64];
  const int t = threadIdx.x;
  const int lane = t & 63, wid = t >> 6;
  const int l15 = lane & 15, quad = lane >> 4;
  const int wm = wid >> 1, wn = wid & 1;
  const int bm = blockIdx.x, bn = blockIdx.y;
  const int lr = lane >> 3;
  const int lc = (lane & 7) * 8;
  f4v acc[4][4] = {};
  if constexpr (WBF) {
    const bf16* Ab = &A[(size_t)(bm * 128 + lr) * HID_DIM + lc];
    const bf16* Bb = &((const bf16*)Wp)[(size_t)(bn * 128 + lr) * HID_DIM + lc];
#pragma unroll
    for (int i = 0; i < 4; ++i) {
      int r0 = wid * 32 + i * 8;
      gload_lds16(Ab + (size_t)r0 * HID_DIM, &As[0][r0 * 64]);
      gload_lds16(Bb + (size_t)r0 * HID_DIM, &Bs[0][r0 * 64]);
    }
    __syncthreads();
    for (int kt = 0; kt < HID_DIM / 64; ++kt) {
      const int cur = kt & 1;
      if (kt + 1 < HID_DIM / 64) {
#pragma unroll
        for (int i = 0; i < 4; ++i) {
          int r0 = wid * 32 + i * 8;
          gload_lds16(Ab + (size_t)r0 * HID_DIM + (kt + 1) * 64, &As[cur ^ 1][r0 * 64]);
          gload_lds16(Bb + (size_t)r0 * HID_DIM + (kt + 1) * 64, &Bs[cur ^ 1][r0 * 64]);
        }
      }
#pragma unroll
      for (int ks = 0; ks < 2; ++ks) {
        s8v af[4], bfr[4];
#pragma unroll
        for (int mi = 0; mi < 4; ++mi)
          af[mi] = *(const s8v*)&As[cur][(wm * 64 + mi * 16 + l15) * 64 + ks * 32 + quad * 8];
#pragma unroll
        for (int ni = 0; ni < 4; ++ni)
          bfr[ni] = *(const s8v*)&Bs[cur][(wn * 64 + ni * 16 + l15) * 64 + ks * 32 + quad * 8];
#pragma unroll
        for (int mi = 0; mi < 4; ++mi)
#pragma unroll
          for (int ni = 0; ni < 4; ++ni)
            acc[mi][ni] = __builtin_amdgcn_mfma_f32_16x16x32_bf16(af[mi], bfr[ni], acc[mi][ni], 0, 0, 0);
      }
      __syncthreads();
    }
  } else {
    for (int kt = 0; kt < HID_DIM / 64; ++kt) {
      __syncthreads();
#pragma unroll
      for (int i = 0; i < 4; ++i) {
        int r0 = wid * 32 + i * 8;
        gload_lds16(&A[(size_t)(bm * 128 + r0 + lr) * HID_DIM + kt * 64 + lc], &As[0][r0 * 64]);
      }
#pragma unroll
      for (int i = 0; i < 4; ++i) {
        int idx = t + i * 256;
        int row = idx >> 3, c8 = (idx & 7) * 8;
        const float* s = (const float*)Wp + (size_t)(bn * 128 + row) * HID_DIM + kt * 64 + c8;
        float4 f0 = *(const float4*)s;
        float4 f1 = *(const float4*)(s + 4);
        s8v tmp;
        tmp[0] = f2b_bits(f0.x); tmp[1] = f2b_bits(f0.y);
        tmp[2] = f2b_bits(f0.z); tmp[3] = f2b_bits(f0.w);
        tmp[4] = f2b_bits(f1.x); tmp[5] = f2b_bits(f1.y);
        tmp[6] = f2b_bits(f1.z); tmp[7] = f2b_bits(f1.w);
        *(s8v*)&Bs[0][row * 64 + c8] = tmp;
      }
      __syncthreads();
#pragma unroll
      for (int ks = 0; ks < 2; ++ks) {
        s8v af[4], bfr[4];
#pragma unroll
        for (int mi = 0; mi < 4; ++mi)
          af[mi] = *(const s8v*)&As[0][(wm * 64 + mi * 16 + l15) * 64 + ks * 32 + quad * 8];
#pragma unroll
        for (int ni = 0; ni < 4; ++ni)
          bfr[ni] = *(const s8v*)&Bs[0][(wn * 64 + ni * 16 + l15) * 64 + ks * 32 + quad * 8];
#pragma unroll
        for (int mi = 0; mi < 4; ++mi)
#pragma unroll
          for (int ni = 0; ni < 4; ++ni)
            acc[mi][ni] = __builtin_amdgcn_mfma_f32_16x16x32_bf16(af[mi], bfr[ni], acc[mi][ni], 0, 0, 0);
      }
    }
  }
#pragma unroll
  for (int ni = 0; ni < 4; ++ni) {
    int col = bn * 128 + wn * 64 + ni * 16 + l15;
    float bvv = bias[col];
#pragma unroll
    for (int mi = 0; mi < 4; ++mi)
#pragma unroll
      for (int r = 0; r < 4; ++r) {
        int row = bm * 128 + wm * 64 + mi * 16 + quad * 4 + r;
        C[(size_t)row * HID_DIM + col] = acc[mi][ni][r] + bvv;
      }
  }
}

// ---------------- Flash attention, G=1, HEAD-MIXED m-tile -------------------
// 256 blocks x 512 threads (8 waves); block (p,b): chunk 255-p then chunk p
// -> exactly 17 KV-tile iterations (KVBLK=128) per block. LDS fragment-major
// FS=528 with fswz interior swizzle (round-2 counters: 2.45e7 conflict cycles
// = 31% of kernel from 8-way fragment-read conflicts).
__global__ __launch_bounds__(512, 2) void attn_fwd(
    const bf16* q, const bf16* __restrict__ k, const bf16* __restrict__ vt,
    bf16* o) {
  constexpr int FS = 528;  // frag stride (bf16)
  __shared__ __align__(16) bf16 KsF[32 * FS];  // frag(ni*4+ks): [l15=n%16][d%32]
  __shared__ __align__(16) bf16 VtF[32 * FS];  // frag(di*4+ks): [l15=d%16][n%32]
  __shared__ __align__(16) bf16 PsF[32 * FS];  // frag(w*4+ks): [l15=m%16][n%32]
  const int t = threadIdx.x;
  const int lane = t & 63, w = t >> 6;  // w in 0..7
  const int l15 = lane & 15, quad = lane >> 4;
  const int p = blockIdx.x >> 1, b = blockIdx.x & 1;
  const size_t bs = (size_t)b * S_LEN;
  const float scale2 = 0.12754245f;  // (1/sqrt(128)) * log2(e)

  for (int cc = 0; cc < 2; ++cc) {
    const int c = cc ? p : (255 - p);
    const int row0 = c * 8;
    const int jt = (c >> 4) + 1;
    const int head = w * 2 + (l15 >> 3);

    // Q fragments: wave covers heads {w*2, w*2+1} x 8 rows (m = 16 virt rows)
    s8v qf[4];
#pragma unroll
    for (int ks = 0; ks < 4; ++ks)
      qf[ks] = *(const s8v*)&q[(bs + row0 + (l15 & 7)) * HID_DIM +
                               head * HEAD_D + ks * 32 + quad * 8];

    float mst = -1e30f;
    float lst = 0.f;
    f4v acco[8] = {};

    uint4 kreg[4], vreg[4];
#pragma unroll
    for (int i = 0; i < 4; ++i) {
      int idx = t + i * 512;
      kreg[i] = *(const uint4*)&k[(bs + (idx >> 4)) * HEAD_D + (idx & 15) * 8];
      vreg[i] = *(const uint4*)&vt[(size_t)(idx >> 4) * M_ROWS + bs + (idx & 15) * 8];
    }

    for (int j = 0; j < jt; ++j) {
      __syncthreads();
#pragma unroll
      for (int i = 0; i < 4; ++i) {
        int idx = t + i * 512;
        int krow = idx >> 4, kc = idx & 15;
        int frag = ((krow >> 4) << 2) | (kc >> 2);
        int intr = fswz(((krow & 15) << 5) + ((kc & 3) << 3));
        *(uint4*)&KsF[frag * FS + intr] = kreg[i];
        *(uint4*)&VtF[frag * FS + intr] = vreg[i];
      }
      if (j + 1 < jt) {
#pragma unroll
        for (int i = 0; i < 4; ++i) {
          int idx = t + i * 512;
          kreg[i] = *(const uint4*)&k[(bs + (j + 1) * 128 + (idx >> 4)) * HEAD_D + (idx & 15) * 8];
          vreg[i] = *(const uint4*)&vt[(size_t)(idx >> 4) * M_ROWS + bs + (j + 1) * 128 + (idx & 15) * 8];
        }
      }
      __syncthreads();

      // S^T[n][m] = K . Q^T  (n = 0..127)
      const int rdi = fswz(l15 * 32 + quad * 8);  // swizzled fragment-read interior
      f4v accs[8] = {};
#pragma unroll
      for (int ks = 0; ks < 4; ++ks) {
        s8v kf[8];
#pragma unroll
        for (int ni = 0; ni < 8; ++ni)
          kf[ni] = *(const s8v*)&KsF[(ni * 4 + ks) * FS + rdi];
#pragma unroll
        for (int ni = 0; ni < 8; ++ni)
          accs[ni] = __builtin_amdgcn_mfma_f32_16x16x32_bf16(kf[ni], qf[ks], accs[ni], 0, 0, 0);
      }

      // online softmax (base-2); causal mask by q-row (head-independent)
      const int mg = row0 + (l15 & 7);
      const bool full = (j * 128 + 127 <= row0);  // uniform
      float tmax = -1e30f;
#pragma unroll
      for (int ni = 0; ni < 8; ++ni)
#pragma unroll
        for (int r = 0; r < 4; ++r) {
          int ng = j * 128 + ni * 16 + quad * 4 + r;
          float s = accs[ni][r];
          if (!full && ng > mg) s = -1e30f;
          accs[ni][r] = s;
          tmax = fmaxf(tmax, s);
        }
      tmax = fmaxf(tmax, __shfl_xor(tmax, 16, 64));
      tmax = fmaxf(tmax, __shfl_xor(tmax, 32, 64));
      float mnew = fmaxf(mst, tmax);
      float nms = -mnew * scale2;
      float alpha = EXP2F(fmaf(mst, scale2, nms));
      float psum = 0.f;
#pragma unroll
      for (int ni = 0; ni < 8; ++ni) {
        float p0 = EXP2F(fmaf(accs[ni][0], scale2, nms));
        float p1 = EXP2F(fmaf(accs[ni][1], scale2, nms));
        float p2 = EXP2F(fmaf(accs[ni][2], scale2, nms));
        float p3 = EXP2F(fmaf(accs[ni][3], scale2, nms));
        psum += (p0 + p1) + (p2 + p3);
        uint2 packed;
        packed.x = pk_bf16(p0, p1);
        packed.y = pk_bf16(p2, p3);
        *(uint2*)&PsF[(w * 4 + (ni >> 1)) * FS +
                      fswz(l15 * 32 + (ni & 1) * 16 + quad * 4)] = packed;
      }
      psum += __shfl_xor(psum, 16, 64);
      psum += __shfl_xor(psum, 32, 64);
      lst = lst * alpha + psum;
      mst = mnew;
#pragma unroll
      for (int r = 0; r < 4; ++r) {
        float ar = __shfl(alpha, quad * 4 + r, 64);
#pragma unroll
        for (int di = 0; di < 8; ++di) acco[di][r] *= ar;
      }

      // O += P @ V
#pragma unroll
      for (int ks = 0; ks < 4; ++ks) {
        s8v pf, vf[8];
        pf = *(const s8v*)&PsF[(w * 4 + ks) * FS + rdi];
#pragma unroll
        for (int di = 0; di < 8; ++di)
          vf[di] = *(const s8v*)&VtF[(di * 4 + ks) * FS + rdi];
#pragma unroll
        for (int di = 0; di < 8; ++di)
          acco[di] = __builtin_amdgcn_mfma_f32_16x16x32_bf16(pf, vf[di], acco[di], 0, 0, 0);
      }
    }

    // epilogue: vm = quad*4+r -> row = row0+(vm&7), head = w*2+(vm>>3)
#pragma unroll
    for (int r = 0; r < 4; ++r) {
      int vmq = quad * 4 + r;
      float lr2 = __shfl(lst, vmq, 64);
      float rinv = 1.0f / lr2;
      size_t row = bs + row0 + (vmq & 7);
      int hd = w * 2 + (vmq >> 3);
#pragma unroll
      for (int di = 0; di < 8; ++di)
        o[row * HID_DIM + hd * HEAD_D + di * 16 + l15] = __float2bfloat16(acco[di][r] * rinv);
    }
  }
}

extern "C" void kernel_launch(void* const* d_in, const int* in_sizes, int n_in,
                              void* d_out, int out_size, void* d_ws, size_t ws_size,
                              hipStream_t stream) {
  const float* hs = (const float*)d_in[0];
  const float* Wq = (const float*)d_in[3];
  const float* bq = (const float*)d_in[4];
  const float* Wk = (const float*)d_in[5];
  const float* bk = (const float*)d_in[6];
  const float* Wv = (const float*)d_in[7];
  const float* bv = (const float*)d_in[8];
  const float* Wo = (const float*)d_in[9];
  const float* bo = (const float*)d_in[10];
  float* out = (float*)d_out;

  bf16* qab = (bf16*)d_ws;  // 16 MB (proven)
  const bool big_ws = ws_size >= (size_t)25 * 1024 * 1024;
  bf16* wob = (bf16*)((char*)d_ws + (size_t)16 * 1024 * 1024);

  // d_out (32 MB) scratch until gemm_o overwrites all of it:
  //   [0,1M): kb  [1M,2M): vtb  [2M,18M): hsb  [18M,27.4M): wqkvb
  char* ob = (char*)d_out;
  bf16* kb = (bf16*)ob;
  bf16* vtb = (bf16*)(ob + (size_t)1048576);
  bf16* hsb = (bf16*)(ob + (size_t)2097152);
  bf16* wqkvb = (bf16*)(ob + (size_t)18874368);

  Cvt5 c;
  c.src[0] = hs; c.dst[0] = hsb;
  c.n8[0] = (long)M_ROWS * HID_DIM / 8;
  c.src[1] = Wq; c.dst[1] = wqkvb;
  c.n8[1] = (long)HID_DIM * HID_DIM / 8;
  c.src[2] = Wk; c.dst[2] = wqkvb + (size_t)HID_DIM * HID_DIM;
  c.n8[2] = (long)HEAD_D * HID_DIM / 8;
  c.src[3] = Wv; c.dst[3] = wqkvb + (size_t)(HID_DIM + HEAD_D) * HID_DIM;
  c.n8[3] = (long)HEAD_D * HID_DIM / 8;
  c.src[4] = Wo; c.dst[4] = big_ws ? wob : (bf16*)nullptr;
  c.n8[4] = big_ws ? (long)HID_DIM * HID_DIM / 8 : 0;
  long total8 = c.n8[0] + c.n8[1] + c.n8[2] + c.n8[3] + c.n8[4];

  cvt_f32_bf16<<<dim3((unsigned)((total8 + 255) / 256)), dim3(256), 0, stream>>>(c);
  gemm_qkv<<<dim3(M_ROWS / 128, N_FUSED / 128), dim3(256), 0, stream>>>(
      hsb, wqkvb, bq, bk, bv, qab, kb, vtb);
  attn_fwd<<<dim3(256), dim3(512), 0, stream>>>(qab, kb, vtb, qab);
  if (big_ws)
    gemm_o<true><<<dim3(M_ROWS / 128, HID_DIM / 128), dim3(256), 0, stream>>>(qab, wob, bo, out);
  else
    gemm_o<false><<<dim3(M_ROWS / 128, HID_DIM / 128), dim3(256), 0, stream>>>(qab, Wo, bo, out);
}

// Round 4
// 362.197 us; speedup vs baseline: 1.0946x; 1.0946x over previous
//
#include <hip/hip_runtime.h>
#include <hip/hip_bf16.h>

typedef __attribute__((ext_vector_type(8))) short s8v;
typedef __attribute__((ext_vector_type(4))) float f4v;
typedef __hip_bfloat16 bf16;

#define S_LEN 2048
#define HID_DIM 2048
#define N_HEADS 16
#define HEAD_D 128
#define M_ROWS 4096
#define N_FUSED 2304  // 2048 q + 128 k + 128 v

#define EXP2F(x) __builtin_amdgcn_exp2f(x)

typedef const __attribute__((address_space(1))) unsigned gu_t;
typedef __attribute__((address_space(3))) unsigned lu_t;

static __device__ inline void gload_lds16(const bf16* g, bf16* l) {
  __builtin_amdgcn_global_load_lds((gu_t*)(const void*)g, (lu_t*)(void*)l, 16, 0, 0);
}

static __device__ inline short f2b_bits(float f) {
  bf16 h = __float2bfloat16(f);
  short u;
  __builtin_memcpy(&u, &h, 2);
  return u;
}
static __device__ inline unsigned pk_bf16(float a, float b) {
  __hip_bfloat162 h2 = __float22bfloat162_rn(float2{a, b});
  unsigned u;
  __builtin_memcpy(&u, &h2, 4);
  return u;
}

// Fragment-interior bank swizzle for attn LDS (bf16-index units, interior<512):
// XOR 16B-slot bits (3-4) with row bits (6-7). Involution applied at BOTH
// write and read sites.
static __device__ inline int fswz(int i) { return i ^ (((i >> 6) & 3) << 3); }

// ---------------- fp32 -> bf16 bulk convert (5 segments, one launch) --------
struct Cvt5 {
  const float* src[5];
  bf16* dst[5];
  long n8[5];
};

__global__ __launch_bounds__(256) void cvt_f32_bf16(Cvt5 c) {
  long i = (long)blockIdx.x * 256 + threadIdx.x;
#pragma unroll
  for (int s = 0; s < 5; ++s) {
    long n8 = c.n8[s];
    if (i < n8) {
      const float* p = c.src[s] + i * 8;
      float4 f0 = *(const float4*)p;
      float4 f1 = *(const float4*)(p + 4);
      s8v t;
      t[0] = f2b_bits(f0.x); t[1] = f2b_bits(f0.y);
      t[2] = f2b_bits(f0.z); t[3] = f2b_bits(f0.w);
      t[4] = f2b_bits(f1.x); t[5] = f2b_bits(f1.y);
      t[6] = f2b_bits(f1.z); t[7] = f2b_bits(f1.w);
      *(s8v*)(c.dst[s] + i * 8) = t;
      return;
    }
    i -= n8;
  }
}

// ---------------- fused QKV GEMM (V written transposed) ---------------------
// BM=64 x BN=128 tile: grid 64x18 = 1152 blocks = 4.5 blocks/CU (m102: the
// blocks/CU count is THE perf lever for the m97 structure: 1/CU=320 TF,
// 4/CU=833 TF). Single-buffered 2-barrier staging (R3's dbuf serialized:
// compiler can't disambiguate As[cur] reads vs DMA writes to As[cur^1]).
// LDS 24 KB -> 4+ blocks resident.
__global__ __launch_bounds__(256) void gemm_qkv(
    const bf16* __restrict__ A, const bf16* __restrict__ Wf,
    const float* __restrict__ bq, const float* __restrict__ bk,
    const float* __restrict__ bv,
    bf16* __restrict__ qout, bf16* __restrict__ kout, bf16* __restrict__ vtout) {
  __shared__ __align__(16) bf16 As[64 * 64];
  __shared__ __align__(16) bf16 Bs[128 * 64];
  const int t = threadIdx.x;
  const int lane = t & 63, wid = t >> 6;
  const int l15 = lane & 15, quad = lane >> 4;
  const int wm = wid >> 1, wn = wid & 1;
  const int bm = blockIdx.x, bn = blockIdx.y;
  const int lr = lane >> 3;        // row within 8-row chunk
  const int lc = (lane & 7) * 8;   // col elements (16B per lane)
  f4v acc[2][4] = {};
  for (int kt = 0; kt < HID_DIM / 64; ++kt) {
    __syncthreads();
#pragma unroll
    for (int i = 0; i < 2; ++i) {
      int r0 = wid * 16 + i * 8;   // A: 64 rows in 8 chunks
      gload_lds16(&A[(size_t)(bm * 64 + r0 + lr) * HID_DIM + kt * 64 + lc], &As[r0 * 64]);
    }
#pragma unroll
    for (int i = 0; i < 4; ++i) {
      int r0 = wid * 32 + i * 8;   // B: 128 rows in 16 chunks
      gload_lds16(&Wf[(size_t)(bn * 128 + r0 + lr) * HID_DIM + kt * 64 + lc], &Bs[r0 * 64]);
    }
    __syncthreads();
#pragma unroll
    for (int ks = 0; ks < 2; ++ks) {
      s8v af[2], bfr[4];
#pragma unroll
      for (int mi = 0; mi < 2; ++mi)
        af[mi] = *(const s8v*)&As[(wm * 32 + mi * 16 + l15) * 64 + ks * 32 + quad * 8];
#pragma unroll
      for (int ni = 0; ni < 4; ++ni)
        bfr[ni] = *(const s8v*)&Bs[(wn * 64 + ni * 16 + l15) * 64 + ks * 32 + quad * 8];
#pragma unroll
      for (int mi = 0; mi < 2; ++mi)
#pragma unroll
        for (int ni = 0; ni < 4; ++ni)
          acc[mi][ni] = __builtin_amdgcn_mfma_f32_16x16x32_bf16(af[mi], bfr[ni], acc[mi][ni], 0, 0, 0);
    }
  }
  if (bn < 16) {
#pragma unroll
    for (int ni = 0; ni < 4; ++ni) {
      int cl = wn * 64 + ni * 16 + l15;
      float bvv = bq[bn * 128 + cl];
#pragma unroll
      for (int mi = 0; mi < 2; ++mi)
#pragma unroll
        for (int r = 0; r < 4; ++r) {
          int row = bm * 64 + wm * 32 + mi * 16 + quad * 4 + r;
          qout[(size_t)row * HID_DIM + bn * 128 + cl] = __float2bfloat16(acc[mi][ni][r] + bvv);
        }
    }
  } else if (bn == 16) {
#pragma unroll
    for (int ni = 0; ni < 4; ++ni) {
      int cl = wn * 64 + ni * 16 + l15;
      float bvv = bk[cl];
#pragma unroll
      for (int mi = 0; mi < 2; ++mi)
#pragma unroll
        for (int r = 0; r < 4; ++r) {
          int row = bm * 64 + wm * 32 + mi * 16 + quad * 4 + r;
          kout[(size_t)row * HEAD_D + cl] = __float2bfloat16(acc[mi][ni][r] + bvv);
        }
    }
  } else {
#pragma unroll
    for (int ni = 0; ni < 4; ++ni) {
      int cl = wn * 64 + ni * 16 + l15;
      float bvv = bv[cl];
#pragma unroll
      for (int mi = 0; mi < 2; ++mi)
#pragma unroll
        for (int r = 0; r < 4; ++r) {
          int row = bm * 64 + wm * 32 + mi * 16 + quad * 4 + r;
          vtout[(size_t)cl * M_ROWS + row] = __float2bfloat16(acc[mi][ni][r] + bvv);
        }
    }
  }
}

// ---------------- O projection -------------------------------------------
// Same BM=64 x BN=128 structure: grid 64x16 = 1024 blocks = 4 blocks/CU.
template <bool WBF>
__global__ __launch_bounds__(256) void gemm_o(
    const bf16* __restrict__ A, const void* __restrict__ Wp,
    const float* __restrict__ bias, float* __restrict__ C) {
  __shared__ __align__(16) bf16 As[64 * 64];
  __shared__ __align__(16) bf16 Bs[128 * 64];
  const int t = threadIdx.x;
  const int lane = t & 63, wid = t >> 6;
  const int l15 = lane & 15, quad = lane >> 4;
  const int wm = wid >> 1, wn = wid & 1;
  const int bm = blockIdx.x, bn = blockIdx.y;
  const int lr = lane >> 3;
  const int lc = (lane & 7) * 8;
  f4v acc[2][4] = {};
  for (int kt = 0; kt < HID_DIM / 64; ++kt) {
    __syncthreads();
#pragma unroll
    for (int i = 0; i < 2; ++i) {
      int r0 = wid * 16 + i * 8;
      gload_lds16(&A[(size_t)(bm * 64 + r0 + lr) * HID_DIM + kt * 64 + lc], &As[r0 * 64]);
    }
    if constexpr (WBF) {
#pragma unroll
      for (int i = 0; i < 4; ++i) {
        int r0 = wid * 32 + i * 8;
        gload_lds16(&((const bf16*)Wp)[(size_t)(bn * 128 + r0 + lr) * HID_DIM + kt * 64 + lc],
                    &Bs[r0 * 64]);
      }
    } else {
#pragma unroll
      for (int i = 0; i < 4; ++i) {
        int idx = t + i * 256;
        int row = idx >> 3, c8 = (idx & 7) * 8;
        const float* s = (const float*)Wp + (size_t)(bn * 128 + row) * HID_DIM + kt * 64 + c8;
        float4 f0 = *(const float4*)s;
        float4 f1 = *(const float4*)(s + 4);
        s8v tmp;
        tmp[0] = f2b_bits(f0.x); tmp[1] = f2b_bits(f0.y);
        tmp[2] = f2b_bits(f0.z); tmp[3] = f2b_bits(f0.w);
        tmp[4] = f2b_bits(f1.x); tmp[5] = f2b_bits(f1.y);
        tmp[6] = f2b_bits(f1.z); tmp[7] = f2b_bits(f1.w);
        *(s8v*)&Bs[row * 64 + c8] = tmp;
      }
    }
    __syncthreads();
#pragma unroll
    for (int ks = 0; ks < 2; ++ks) {
      s8v af[2], bfr[4];
#pragma unroll
      for (int mi = 0; mi < 2; ++mi)
        af[mi] = *(const s8v*)&As[(wm * 32 + mi * 16 + l15) * 64 + ks * 32 + quad * 8];
#pragma unroll
      for (int ni = 0; ni < 4; ++ni)
        bfr[ni] = *(const s8v*)&Bs[(wn * 64 + ni * 16 + l15) * 64 + ks * 32 + quad * 8];
#pragma unroll
      for (int mi = 0; mi < 2; ++mi)
#pragma unroll
        for (int ni = 0; ni < 4; ++ni)
          acc[mi][ni] = __builtin_amdgcn_mfma_f32_16x16x32_bf16(af[mi], bfr[ni], acc[mi][ni], 0, 0, 0);
    }
  }
#pragma unroll
  for (int ni = 0; ni < 4; ++ni) {
    int col = bn * 128 + wn * 64 + ni * 16 + l15;
    float bvv = bias[col];
#pragma unroll
    for (int mi = 0; mi < 2; ++mi)
#pragma unroll
      for (int r = 0; r < 4; ++r) {
        int row = bm * 64 + wm * 32 + mi * 16 + quad * 4 + r;
        C[(size_t)row * HID_DIM + col] = acc[mi][ni][r] + bvv;
      }
  }
}

// ---------------- Flash attention, G=1, HEAD-MIXED m-tile -------------------
// 256 blocks x 512 threads (8 waves); block (p,b): chunk 255-p then chunk p
// -> exactly 17 KV-tile iterations (KVBLK=128) per block. LDS fragment-major
// FS=528 with fswz interior swizzle. T5 setprio around MFMA clusters.
__global__ __launch_bounds__(512, 2) void attn_fwd(
    const bf16* q, const bf16* __restrict__ k, const bf16* __restrict__ vt,
    bf16* o) {
  constexpr int FS = 528;  // frag stride (bf16)
  __shared__ __align__(16) bf16 KsF[32 * FS];  // frag(ni*4+ks): [l15=n%16][d%32]
  __shared__ __align__(16) bf16 VtF[32 * FS];  // frag(di*4+ks): [l15=d%16][n%32]
  __shared__ __align__(16) bf16 PsF[32 * FS];  // frag(w*4+ks): [l15=m%16][n%32]
  const int t = threadIdx.x;
  const int lane = t & 63, w = t >> 6;  // w in 0..7
  const int l15 = lane & 15, quad = lane >> 4;
  const int p = blockIdx.x >> 1, b = blockIdx.x & 1;
  const size_t bs = (size_t)b * S_LEN;
  const float scale2 = 0.12754245f;  // (1/sqrt(128)) * log2(e)

  for (int cc = 0; cc < 2; ++cc) {
    const int c = cc ? p : (255 - p);
    const int row0 = c * 8;
    const int jt = (c >> 4) + 1;
    const int head = w * 2 + (l15 >> 3);

    // Q fragments: wave covers heads {w*2, w*2+1} x 8 rows (m = 16 virt rows)
    s8v qf[4];
#pragma unroll
    for (int ks = 0; ks < 4; ++ks)
      qf[ks] = *(const s8v*)&q[(bs + row0 + (l15 & 7)) * HID_DIM +
                               head * HEAD_D + ks * 32 + quad * 8];

    float mst = -1e30f;
    float lst = 0.f;
    f4v acco[8] = {};

    uint4 kreg[4], vreg[4];
#pragma unroll
    for (int i = 0; i < 4; ++i) {
      int idx = t + i * 512;
      kreg[i] = *(const uint4*)&k[(bs + (idx >> 4)) * HEAD_D + (idx & 15) * 8];
      vreg[i] = *(const uint4*)&vt[(size_t)(idx >> 4) * M_ROWS + bs + (idx & 15) * 8];
    }

    for (int j = 0; j < jt; ++j) {
      __syncthreads();
#pragma unroll
      for (int i = 0; i < 4; ++i) {
        int idx = t + i * 512;
        int krow = idx >> 4, kc = idx & 15;
        int frag = ((krow >> 4) << 2) | (kc >> 2);
        int intr = fswz(((krow & 15) << 5) + ((kc & 3) << 3));
        *(uint4*)&KsF[frag * FS + intr] = kreg[i];
        *(uint4*)&VtF[frag * FS + intr] = vreg[i];
      }
      if (j + 1 < jt) {
#pragma unroll
        for (int i = 0; i < 4; ++i) {
          int idx = t + i * 512;
          kreg[i] = *(const uint4*)&k[(bs + (j + 1) * 128 + (idx >> 4)) * HEAD_D + (idx & 15) * 8];
          vreg[i] = *(const uint4*)&vt[(size_t)(idx >> 4) * M_ROWS + bs + (j + 1) * 128 + (idx & 15) * 8];
        }
      }
      __syncthreads();

      // S^T[n][m] = K . Q^T  (n = 0..127)
      const int rdi = fswz(l15 * 32 + quad * 8);  // swizzled fragment-read interior
      f4v accs[8] = {};
      __builtin_amdgcn_s_setprio(1);
#pragma unroll
      for (int ks = 0; ks < 4; ++ks) {
        s8v kf[8];
#pragma unroll
        for (int ni = 0; ni < 8; ++ni)
          kf[ni] = *(const s8v*)&KsF[(ni * 4 + ks) * FS + rdi];
#pragma unroll
        for (int ni = 0; ni < 8; ++ni)
          accs[ni] = __builtin_amdgcn_mfma_f32_16x16x32_bf16(kf[ni], qf[ks], accs[ni], 0, 0, 0);
      }
      __builtin_amdgcn_s_setprio(0);

      // online softmax (base-2); causal mask by q-row (head-independent)
      const int mg = row0 + (l15 & 7);
      const bool full = (j * 128 + 127 <= row0);  // uniform
      float tmax = -1e30f;
#pragma unroll
      for (int ni = 0; ni < 8; ++ni)
#pragma unroll
        for (int r = 0; r < 4; ++r) {
          int ng = j * 128 + ni * 16 + quad * 4 + r;
          float s = accs[ni][r];
          if (!full && ng > mg) s = -1e30f;
          accs[ni][r] = s;
          tmax = fmaxf(tmax, s);
        }
      tmax = fmaxf(tmax, __shfl_xor(tmax, 16, 64));
      tmax = fmaxf(tmax, __shfl_xor(tmax, 32, 64));
      float mnew = fmaxf(mst, tmax);
      float nms = -mnew * scale2;
      float alpha = EXP2F(fmaf(mst, scale2, nms));
      float psum = 0.f;
#pragma unroll
      for (int ni = 0; ni < 8; ++ni) {
        float p0 = EXP2F(fmaf(accs[ni][0], scale2, nms));
        float p1 = EXP2F(fmaf(accs[ni][1], scale2, nms));
        float p2 = EXP2F(fmaf(accs[ni][2], scale2, nms));
        float p3 = EXP2F(fmaf(accs[ni][3], scale2, nms));
        psum += (p0 + p1) + (p2 + p3);
        uint2 packed;
        packed.x = pk_bf16(p0, p1);
        packed.y = pk_bf16(p2, p3);
        *(uint2*)&PsF[(w * 4 + (ni >> 1)) * FS +
                      fswz(l15 * 32 + (ni & 1) * 16 + quad * 4)] = packed;
      }
      psum += __shfl_xor(psum, 16, 64);
      psum += __shfl_xor(psum, 32, 64);
      lst = lst * alpha + psum;
      mst = mnew;
#pragma unroll
      for (int r = 0; r < 4; ++r) {
        float ar = __shfl(alpha, quad * 4 + r, 64);
#pragma unroll
        for (int di = 0; di < 8; ++di) acco[di][r] *= ar;
      }

      // O += P @ V
      __builtin_amdgcn_s_setprio(1);
#pragma unroll
      for (int ks = 0; ks < 4; ++ks) {
        s8v pf, vf[8];
        pf = *(const s8v*)&PsF[(w * 4 + ks) * FS + rdi];
#pragma unroll
        for (int di = 0; di < 8; ++di)
          vf[di] = *(const s8v*)&VtF[(di * 4 + ks) * FS + rdi];
#pragma unroll
        for (int di = 0; di < 8; ++di)
          acco[di] = __builtin_amdgcn_mfma_f32_16x16x32_bf16(pf, vf[di], acco[di], 0, 0, 0);
      }
      __builtin_amdgcn_s_setprio(0);
    }

    // epilogue: vm = quad*4+r -> row = row0+(vm&7), head = w*2+(vm>>3)
#pragma unroll
    for (int r = 0; r < 4; ++r) {
      int vmq = quad * 4 + r;
      float lr2 = __shfl(lst, vmq, 64);
      float rinv = 1.0f / lr2;
      size_t row = bs + row0 + (vmq & 7);
      int hd = w * 2 + (vmq >> 3);
#pragma unroll
      for (int di = 0; di < 8; ++di)
        o[row * HID_DIM + hd * HEAD_D + di * 16 + l15] = __float2bfloat16(acco[di][r] * rinv);
    }
  }
}

extern "C" void kernel_launch(void* const* d_in, const int* in_sizes, int n_in,
                              void* d_out, int out_size, void* d_ws, size_t ws_size,
                              hipStream_t stream) {
  const float* hs = (const float*)d_in[0];
  const float* Wq = (const float*)d_in[3];
  const float* bq = (const float*)d_in[4];
  const float* Wk = (const float*)d_in[5];
  const float* bk = (const float*)d_in[6];
  const float* Wv = (const float*)d_in[7];
  const float* bv = (const float*)d_in[8];
  const float* Wo = (const float*)d_in[9];
  const float* bo = (const float*)d_in[10];
  float* out = (float*)d_out;

  bf16* qab = (bf16*)d_ws;  // 16 MB (proven)
  const bool big_ws = ws_size >= (size_t)25 * 1024 * 1024;
  bf16* wob = (bf16*)((char*)d_ws + (size_t)16 * 1024 * 1024);

  // d_out (32 MB) scratch until gemm_o overwrites all of it:
  //   [0,1M): kb  [1M,2M): vtb  [2M,18M): hsb  [18M,27.4M): wqkvb
  char* ob = (char*)d_out;
  bf16* kb = (bf16*)ob;
  bf16* vtb = (bf16*)(ob + (size_t)1048576);
  bf16* hsb = (bf16*)(ob + (size_t)2097152);
  bf16* wqkvb = (bf16*)(ob + (size_t)18874368);

  Cvt5 c;
  c.src[0] = hs; c.dst[0] = hsb;
  c.n8[0] = (long)M_ROWS * HID_DIM / 8;
  c.src[1] = Wq; c.dst[1] = wqkvb;
  c.n8[1] = (long)HID_DIM * HID_DIM / 8;
  c.src[2] = Wk; c.dst[2] = wqkvb + (size_t)HID_DIM * HID_DIM;
  c.n8[2] = (long)HEAD_D * HID_DIM / 8;
  c.src[3] = Wv; c.dst[3] = wqkvb + (size_t)(HID_DIM + HEAD_D) * HID_DIM;
  c.n8[3] = (long)HEAD_D * HID_DIM / 8;
  c.src[4] = Wo; c.dst[4] = big_ws ? wob : (bf16*)nullptr;
  c.n8[4] = big_ws ? (long)HID_DIM * HID_DIM / 8 : 0;
  long total8 = c.n8[0] + c.n8[1] + c.n8[2] + c.n8[3] + c.n8[4];

  cvt_f32_bf16<<<dim3((unsigned)((total8 + 255) / 256)), dim3(256), 0, stream>>>(c);
  gemm_qkv<<<dim3(M_ROWS / 64, N_FUSED / 128), dim3(256), 0, stream>>>(
      hsb, wqkvb, bq, bk, bv, qab, kb, vtb);
  attn_fwd<<<dim3(256), dim3(512), 0, stream>>>(qab, kb, vtb, qab);
  if (big_ws)
    gemm_o<true><<<dim3(M_ROWS / 64, HID_DIM / 128), dim3(256), 0, stream>>>(qab, wob, bo, out);
  else
    gemm_o<false><<<dim3(M_ROWS / 64, HID_DIM / 128), dim3(256), 0, stream>>>(qab, Wo, bo, out);
}